// Round 1
// 148.956 us; speedup vs baseline: 1.0330x; 1.0330x over previous
//
#include <hip/hip_runtime.h>

#define OUTS 14
#define GRIDG 28   // OUTS * sampling_ratio(2)
#define NLEV 4
#define NPIX (OUTS*OUTS)   // 196
#define CG   32            // channels per block
#define NCG  8             // 256 / CG

// v2: the 102.8 MB output zero-fill is moved OUT of the kernel into a
// hipMemsetAsync node (rocclr fill measured at 6.7-6.8 TB/s on this chip —
// 84-85% of peak — vs our in-kernel streaming store that shared issue slots
// with coord-prep phases and 3 __syncthreads at 5 blocks/CU LDS-capped
// occupancy). The kernel is now sparse-only:
//
// Grid: 1D, R*NCG blocks; roi = bx>>3, chgroup = bx&7.
// Phase 1: torchvision bilinear coord prep per (axis, level, gridpoint) -> LDS,
//          cumulative roi scaling with __f*_rn (no FMA contraction) to match
//          reference validity-boundary comparisons. Per-(axis,level) any-valid
//          flags.
// Phase 2: per-pixel activity + compacted active-pixel list (atomicAdd on LDS).
//          s_nact == 0 (the ~95% case: levels 0/1 structurally all-invalid,
//          level 2 needs tl < 0.0023, level 3 needs tl < ~0.13) -> block
//          returns having touched no global memory; memset already wrote the
//          max(...,0) floor the reference produces for masked-out samples.
// Phase 3: for each roi-active level: 196 threads build a per-pixel table of
//          16 (index, weight) pairs ONCE (weights are channel-independent);
//          then threads (cl=tid>>3, k=tid&7) sweep (channel, active-pixel)
//          pairs: 16 LDS table reads + 16 batched L2-resident gathers + FMA,
//          and load-max-store into the pre-zeroed output. Each (r,c,p) is
//          RMW'd by exactly one thread across all levels -> no races.
__global__ __launch_bounds__(256) void afp_kernel(
    const float* __restrict__ f0, const float* __restrict__ f1,
    const float* __restrict__ f2, const float* __restrict__ f3,
    const float* __restrict__ rois, float* __restrict__ out,
    int R, int C)
{
    __shared__ int   s_lo[2][NLEV][GRIDG];
    __shared__ int   s_hi[2][NLEV][GRIDG];
    __shared__ float s_fr[2][NLEV][GRIDG];
    __shared__ int   s_va[2][NLEV][GRIDG];
    __shared__ int   s_axany[2][NLEV];
    __shared__ int   s_plist[NPIX];
    __shared__ int   s_nact;
    __shared__ int   s_tidx[NPIX][16];
    __shared__ float s_tw[NPIX][16];

    const int bx  = blockIdx.x;
    const int r   = bx >> 3;
    const int cg  = bx & 7;
    const int tid = threadIdx.x;
    const int HS[NLEV] = {224, 112, 56, 28};
    const float* const fp[NLEV] = {f0, f1, f2, f3};
    const int cbase = cg * CG;

    if (tid < 2 * NLEV) (&s_axany[0][0])[tid] = 0;
    if (tid == 0) s_nact = 0;
    __syncthreads();

    // ---- phase 1: coordinate prep (224 work items) ----
    if (tid < 2 * NLEV * GRIDG) {
        int lv   = tid / (2 * GRIDG);
        int rem  = tid - lv * 2 * GRIDG;
        int axis = rem / GRIDG;          // 0 = y, 1 = x
        int g    = rem - axis * GRIDG;

        float x1 = rois[4*r+0], y1 = rois[4*r+1];
        float x2 = rois[4*r+2], y2 = rois[4*r+3];
        for (int j = 3; j >= lv; --j) {   // cumulative scale, reference order
            float f = (float)(28 << j);
            x1 = __fmul_rn(x1, f); y1 = __fmul_rn(y1, f);
            x2 = __fmul_rn(x2, f); y2 = __fmul_rn(y2, f);
        }
        float lo_c = axis ? x1 : y1;
        float hi_c = axis ? x2 : y2;
        int   Li = HS[lv];
        float Lf = (float)Li;

        float span = fmaxf(__fsub_rn(hi_c, lo_c), 1.0f);
        float bin  = __fdiv_rn(span, (float)OUTS);
        float step = ((float)g + 0.5f) * 0.5f;          // (g+0.5)/sr, exact
        float c    = __fadd_rn(lo_c, __fmul_rn(step, bin));

        int valid = (c >= -1.0f) && (c <= Lf);
        float cc  = fminf(fmaxf(c, 0.0f), Lf - 1.0f);
        float fl  = floorf(cc);
        float fr  = __fsub_rn(cc, fl);
        int lo = (int)fl, hi = lo + 1;
        if (lo >= Li - 1) { lo = Li - 1; hi = Li - 1; fr = 0.0f; }

        s_lo[axis][lv][g] = lo;  s_hi[axis][lv][g] = hi;
        s_fr[axis][lv][g] = fr;  s_va[axis][lv][g] = valid;
        if (valid) s_axany[axis][lv] = 1;
    }
    __syncthreads();

    // ---- phase 2: per-pixel activity + compacted list ----
    if (tid < NPIX) {
        int oy = tid / OUTS, ox = tid - oy * OUTS;
        int gy = 2 * oy, gx = 2 * ox;
        int act = 0;
        #pragma unroll
        for (int lv = 0; lv < NLEV; ++lv) {
            int ay = s_va[0][lv][gy] | s_va[0][lv][gy+1];
            int ax = s_va[1][lv][gx] | s_va[1][lv][gx+1];
            act |= (ay & ax);
        }
        if (act) {
            int pos = atomicAdd(&s_nact, 1);
            s_plist[pos] = tid;
        }
    }
    __syncthreads();

    if (s_nact == 0) return;   // block-uniform: ~95% of blocks exit here

    // ---- phase 3: per active level, table build + channel sweep ----
    for (int lv = 0; lv < NLEV; ++lv) {
        if (!(s_axany[0][lv] & s_axany[1][lv])) continue;    // block-uniform

        if (tid < NPIX) {
            int oy = tid / OUTS, ox = tid - oy * OUTS;
            int gy = 2 * oy, gx = 2 * ox;
            int W = HS[lv];
            #pragma unroll
            for (int sy = 0; sy < 2; ++sy) {
                int   yv  = s_va[0][lv][gy+sy];
                int   ylo = s_lo[0][lv][gy+sy] * W;
                int   yhi = s_hi[0][lv][gy+sy] * W;
                float fy  = s_fr[0][lv][gy+sy];
                #pragma unroll
                for (int sx = 0; sx < 2; ++sx) {
                    int   xv  = s_va[1][lv][gx+sx];
                    int   xlo = s_lo[1][lv][gx+sx];
                    int   xhi = s_hi[1][lv][gx+sx];
                    float fx  = s_fr[1][lv][gx+sx];
                    float m   = (yv & xv) ? 1.0f : 0.0f;
                    int e = (sy * 2 + sx) * 4;
                    s_tidx[tid][e+0] = ylo + xlo;  s_tw[tid][e+0] = m * (1.0f-fy) * (1.0f-fx);
                    s_tidx[tid][e+1] = ylo + xhi;  s_tw[tid][e+1] = m * (1.0f-fy) * fx;
                    s_tidx[tid][e+2] = yhi + xlo;  s_tw[tid][e+2] = m * fy * (1.0f-fx);
                    s_tidx[tid][e+3] = yhi + xhi;  s_tw[tid][e+3] = m * fy * fx;
                }
            }
        }
        __syncthreads();

        const int W = HS[lv];
        const int cl = tid >> 3;          // 0..31 channel within group
        const int k  = tid & 7;
        const float* __restrict__ base = fp[lv] + (size_t)(cbase + cl) * W * W;
        const int nact = s_nact;
        for (int pi = k; pi < nact; pi += 8) {
            int p = s_plist[pi];
            float acc = 0.0f;
            #pragma unroll
            for (int e = 0; e < 16; ++e)
                acc += s_tw[p][e] * base[s_tidx[p][e]];
            float val = acc * 0.25f;
            size_t off = ((size_t)r * C + cbase + cl) * NPIX + p;
            float old = out[off];                 // pre-zeroed by memset node
            out[off] = fmaxf(old, val);           // running max across levels
        }
        __syncthreads();
    }
}

extern "C" void kernel_launch(void* const* d_in, const int* in_sizes, int n_in,
                              void* d_out, int out_size, void* d_ws, size_t ws_size,
                              hipStream_t stream) {
    const float* f0   = (const float*)d_in[0];
    const float* f1   = (const float*)d_in[1];
    const float* f2   = (const float*)d_in[2];
    const float* f3   = (const float*)d_in[3];
    const float* rois = (const float*)d_in[4];
    float* out = (float*)d_out;

    int R = in_sizes[4] / 4;                 // 512
    int C = in_sizes[3] / (28 * 28);         // 256

    // Zero the 102.8 MB output at rocclr-fill speed (measured 6.7-6.8 TB/s on
    // this chip) instead of in-kernel streaming stores. Stream-ordered, so the
    // kernel's load-max-store sees the zeros.
    hipMemsetAsync(out, 0, out_size, stream);

    afp_kernel<<<R * NCG, 256, 0, stream>>>(f0, f1, f2, f3, rois, out, R, C);
}